// Round 15
// baseline (263.013 us; speedup 1.0000x reference)
//
#include <hip/hip_runtime.h>
#include <hip/hip_bf16.h>
#include <math.h>

#define NN 10000
#define NE 160000
#define NG 20
#define NZ 10
#define INV_AVG 0.0625f
#define PSTRIDE 76    // LDS row stride (elems): 8B-aligned, conflict-free
#define NSTR 1040     // einsum_gate sNew node stride (elems)

typedef __attribute__((ext_vector_type(8))) short bf16x8;
typedef __attribute__((ext_vector_type(4))) float f32x4;
typedef __attribute__((ext_vector_type(4))) unsigned short u16x4;
typedef __attribute__((ext_vector_type(8))) unsigned short u16x8;

// fast silu: rcp is ~1ulp@2^-22 — outputs are bf16-rounded anyway
__device__ __forceinline__ float silu(float x) {
    return x * __builtin_amdgcn_rcpf(1.0f + __expf(-x));
}

__device__ __forceinline__ unsigned short f2b(float f) {
    union { float f; unsigned u; } v; v.f = f;
    unsigned r = v.u + 0x7FFF + ((v.u >> 16) & 1);
    return (unsigned short)(r >> 16);
}
__device__ __forceinline__ float b2f(unsigned short h) {
    union { unsigned u; float f; } v; v.u = ((unsigned)h) << 16; return v.f;
}

// ---------------------------------------------------------------------------
// feats0 = node_attrs @ W_embed ; node_en[n] = node_attrs @ atomic_energies
// ---------------------------------------------------------------------------
__global__ __launch_bounds__(256) void node_init(
    const float* __restrict__ attrs, const float* __restrict__ W_embed,
    const float* __restrict__ ae,
    float* __restrict__ feats, float* __restrict__ node_en)
{
    int gid = blockIdx.x * blockDim.x + threadIdx.x;
    if (gid >= NN * 64) return;
    int n = gid >> 6, k = gid & 63;
    float acc = 0.f;
#pragma unroll
    for (int z = 0; z < NZ; ++z) acc += attrs[n * NZ + z] * W_embed[z * 64 + k];
    feats[gid] = acc;
    if (k == 0) {
        float e0 = 0.f;
#pragma unroll
        for (int z = 0; z < NZ; ++z) e0 += attrs[n * NZ + z] * ae[z];
        node_en[n] = e0;
    }
}

// ---------------------------------------------------------------------------
// CSR build
// ---------------------------------------------------------------------------
__global__ __launch_bounds__(256) void csr_count(const int* __restrict__ ei, int* __restrict__ cnt)
{
    int e = blockIdx.x * 256 + threadIdx.x;
    if (e < NE) atomicAdd(&cnt[ei[NE + e]], 1);
}

__global__ __launch_bounds__(1024) void csr_scan(const int* __restrict__ cnt, int* __restrict__ row)
{
    __shared__ int part[1024];
    const int tid = threadIdx.x;
    const int base = tid * 10;
    int loc[10];
    int s = 0;
#pragma unroll
    for (int q = 0; q < 10; ++q) {
        int idx = base + q;
        int v = (idx < NN) ? cnt[idx] : 0;
        loc[q] = s; s += v;
    }
    part[tid] = s;
    __syncthreads();
    for (int off = 1; off < 1024; off <<= 1) {
        int v = (tid >= off) ? part[tid - off] : 0;
        __syncthreads();
        part[tid] += v;
        __syncthreads();
    }
    int pre = (tid > 0) ? part[tid - 1] : 0;
#pragma unroll
    for (int q = 0; q < 10; ++q) {
        int idx = base + q;
        if (idx < NN) row[idx] = pre + loc[q];
    }
    if (tid == 1023) row[NN] = part[1023];
}

__global__ __launch_bounds__(256) void csr_scatter(
    const int* __restrict__ ei, const int* __restrict__ row,
    int* __restrict__ cur, int* __restrict__ perm)
{
    int e = blockIdx.x * 256 + threadIdx.x;
    if (e < NE) {
        int r = ei[NE + e];
        int p = atomicAdd(&cur[r], 1);
        perm[row[r] + p] = e;
    }
}

// ---------------------------------------------------------------------------
// w_prep: pack radial + Wmix weights into bf16 MFMA fragment order:
// fragment (kt,nt), lane l, elem j holds W[kt*32 + (l>>4)*8 + j][nt*16 + (l&15)].
// ---------------------------------------------------------------------------
__global__ __launch_bounds__(256) void w_prep(
    const float* __restrict__ rW0, const float* __restrict__ rW1,
    const float* __restrict__ rW2, const float* __restrict__ rW3,
    const float* __restrict__ Wmix,
    unsigned short* __restrict__ w0f, unsigned short* __restrict__ w1f,
    unsigned short* __restrict__ w2f, unsigned short* __restrict__ w3f,
    unsigned short* __restrict__ wmixf)
{
    int g = blockIdx.x * 256 + threadIdx.x;   // 102400 total
    if (g < 4096) {
        int t = g >> 11, x = g & 2047;
        int nt = x >> 9, l = (x >> 3) & 63, j = x & 7;
        int k = (l >> 4) * 8 + j, c = nt * 16 + (l & 15);
        w0f[g] = (k < 8) ? f2b(rW0[t * 512 + k * 64 + c]) : (unsigned short)0;
    } else if (g < 20480) {
        int x0 = g - 4096;
        int t = x0 >> 13, x = x0 & 8191;
        int fidx = x >> 9, l = (x >> 3) & 63, j = x & 7;
        int kt = fidx >> 2, nt = fidx & 3;
        int k = kt * 32 + (l >> 4) * 8 + j, c = nt * 16 + (l & 15);
        w1f[x0] = f2b(rW1[t * 4096 + k * 64 + c]);
    } else if (g < 36864) {
        int x0 = g - 20480;
        int t = x0 >> 13, x = x0 & 8191;
        int fidx = x >> 9, l = (x >> 3) & 63, j = x & 7;
        int kt = fidx >> 2, nt = fidx & 3;
        int k = kt * 32 + (l >> 4) * 8 + j, c = nt * 16 + (l & 15);
        w2f[x0] = f2b(rW2[t * 4096 + k * 64 + c]);
    } else if (g < 69632) {
        int x0 = g - 36864;
        int t = x0 >> 14, x = x0 & 16383;
        int fidx = x >> 9, l = (x >> 3) & 63, j = x & 7;
        int kt = fidx >> 4, nt = fidx & 15;
        int k = kt * 32 + (l >> 4) * 8 + j, c = nt * 16 + (l & 15);
        w3f[x0] = f2b(rW3[t * 16384 + k * 256 + c]);
    } else if (g < 102400) {
        int x0 = g - 69632;
        int t = x0 >> 14;
        int x = x0 & 16383;
        int l = x >> 12;
        int xx = x & 4095;
        int f = xx >> 9, ll = (xx >> 3) & 63, j = xx & 7;
        int kt = f >> 2, ct = f & 3;
        int k = kt * 32 + (ll >> 4) * 8 + j, c = ct * 16 + (ll & 15);
        wmixf[x0] = f2b(Wmix[t * 16384 + l * 4096 + k * 64 + c]);
    }
}

// ---------------------------------------------------------------------------
// edge_geom (runs ONCE): per PERMUTED edge slot g, compute Y (bf16), radial
// basis eb (bf16), and sender index. All outputs receiver-sorted.
// ---------------------------------------------------------------------------
__global__ __launch_bounds__(256) void edge_geom(
    const int* __restrict__ ei, const float* __restrict__ pos,
    const int* __restrict__ perm,
    unsigned short* __restrict__ ybg, unsigned short* __restrict__ ebg,
    int* __restrict__ snd_p)
{
    const int g = blockIdx.x * 256 + threadIdx.x;   // grid covers exactly NE
    const int e = perm[g];
    const int snd = ei[e], rcv = ei[NE + e];
    snd_p[g] = snd;
    const float dx = pos[rcv * 3 + 0] - pos[snd * 3 + 0];
    const float dy = pos[rcv * 3 + 1] - pos[snd * 3 + 1];
    const float dz = pos[rcv * 3 + 2] - pos[snd * 3 + 2];
    const float r = sqrtf(dx * dx + dy * dy + dz * dz + 1e-12f);
    const float ir = 1.0f / r;
    const float x = dx * ir, y = dy * ir, z = dz * ir;
    const float xx = x * x, yy = y * y, zz = z * z;

    u16x8 ylo, yhi;
    ylo[0] = f2b(1.0f);
    ylo[1] = f2b(1.73205081f * x);
    ylo[2] = f2b(1.73205081f * y);
    ylo[3] = f2b(1.73205081f * z);
    ylo[4] = f2b(3.87298335f * x * y);
    ylo[5] = f2b(3.87298335f * y * z);
    ylo[6] = f2b(1.11803399f * (3.0f * zz - 1.0f));
    ylo[7] = f2b(3.87298335f * x * z);
    yhi[0] = f2b(1.93649167f * (xx - yy));
    yhi[1] = f2b(2.09165007f * y * (3.0f * xx - yy));
    yhi[2] = f2b(10.2469508f * x * y * z);
    yhi[3] = f2b(1.62018517f * y * (5.0f * zz - 1.0f));
    yhi[4] = f2b(1.32287566f * z * (5.0f * zz - 3.0f));
    yhi[5] = f2b(1.62018517f * x * (5.0f * zz - 1.0f));
    yhi[6] = f2b(5.12347538f * z * (xx - yy));
    yhi[7] = f2b(2.09165007f * x * (xx - 3.0f * yy));
    *(u16x8*)&ybg[(size_t)g * 16] = ylo;
    *(u16x8*)&ybg[(size_t)g * 16 + 8] = yhi;

    const float u = r * 0.2f;
    float env = 0.0f;
    if (u < 1.0f) {
        const float u2 = u * u, u5 = u2 * u2 * u;
        env = 1.0f - 21.0f * u5 + 35.0f * u5 * u - 15.0f * u5 * u2;
    }
    const float cb = 0.632455532f * ir * env;
    const float pu = 3.14159265358979f * u;
    u16x8 eb;
#pragma unroll
    for (int i = 0; i < 8; ++i) eb[i] = f2b(cb * __sinf((float)(i + 1) * pu));
    *(u16x8*)&ebg[(size_t)g * 8] = eb;
}

// ---------------------------------------------------------------------------
// radial_fused: TWO 16-edge tiles per wave, interleaved stage-by-stage for
// ILP (weight fragments shared). SINGLE LDS buffer per tile: within a wave,
// DS ops execute in program order, so a layer's b128 reads (issued first)
// complete before its u16x4 writes to the same rows — no ping/pong needed.
// LDS stays 19456 B/block. Layer-4 stores: two sequential per-tile loops
// (round-14's exact 80 MB pattern). All-swapped-operand MFMAs.
// ---------------------------------------------------------------------------
__global__ __launch_bounds__(256) void radial_fused(
    const unsigned short* __restrict__ ebg,
    const unsigned short* __restrict__ w0f,
    const unsigned short* __restrict__ w1f,
    const unsigned short* __restrict__ w2f,
    const unsigned short* __restrict__ w3f,
    unsigned short* __restrict__ rwb)
{
    __shared__ unsigned short sP[4][2][16 * PSTRIDE];
    const int w = threadIdx.x >> 6, lane = threadIdx.x & 63;
    const int lg = lane >> 4, e16 = lane & 15;
    unsigned short* buf0 = &sP[w][0][0];
    unsigned short* buf1 = &sP[w][1][0];

    const size_t g0 = ((size_t)blockIdx.x * 8 + w * 2) * 16;
    const size_t g1 = g0 + 16;

    f32x4 c0[4], c1[4];

    // ---- layer 1 (swapped): C[ch][edge] ----
    bf16x8 a0 = {0, 0, 0, 0, 0, 0, 0, 0};
    bf16x8 a1 = {0, 0, 0, 0, 0, 0, 0, 0};
    if (lg == 0) {
        a0 = *(const bf16x8*)&ebg[(g0 + e16) * 8];
        a1 = *(const bf16x8*)&ebg[(g1 + e16) * 8];
    }
#pragma unroll
    for (int nt = 0; nt < 4; ++nt) {
        const bf16x8 b = *(const bf16x8*)&w0f[nt * 512 + lane * 8];
        c0[nt] = __builtin_amdgcn_mfma_f32_16x16x32_bf16(b, a0, (f32x4){0.f, 0.f, 0.f, 0.f}, 0, 0, 0);
        c1[nt] = __builtin_amdgcn_mfma_f32_16x16x32_bf16(b, a1, (f32x4){0.f, 0.f, 0.f, 0.f}, 0, 0, 0);
    }
#pragma unroll
    for (int nt = 0; nt < 4; ++nt) {
        u16x4 o0, o1;
#pragma unroll
        for (int jj = 0; jj < 4; ++jj) { o0[jj] = f2b(silu(c0[nt][jj])); o1[jj] = f2b(silu(c1[nt][jj])); }
        *(u16x4*)&buf0[e16 * PSTRIDE + nt * 16 + lg * 4] = o0;
        *(u16x4*)&buf1[e16 * PSTRIDE + nt * 16 + lg * 4] = o1;
    }

    // ---- layer 2 (swapped, single-buffer: reads precede writes in order) ----
    {
        const bf16x8 p00 = *(const bf16x8*)&buf0[e16 * PSTRIDE + lg * 8];
        const bf16x8 p01 = *(const bf16x8*)&buf0[e16 * PSTRIDE + 32 + lg * 8];
        const bf16x8 p10 = *(const bf16x8*)&buf1[e16 * PSTRIDE + lg * 8];
        const bf16x8 p11 = *(const bf16x8*)&buf1[e16 * PSTRIDE + 32 + lg * 8];
#pragma unroll
        for (int nt = 0; nt < 4; ++nt) {
            const bf16x8 b0 = *(const bf16x8*)&w1f[nt * 512 + lane * 8];
            const bf16x8 b1 = *(const bf16x8*)&w1f[(4 + nt) * 512 + lane * 8];
            f32x4 t0 = __builtin_amdgcn_mfma_f32_16x16x32_bf16(b0, p00, (f32x4){0.f, 0.f, 0.f, 0.f}, 0, 0, 0);
            f32x4 t1 = __builtin_amdgcn_mfma_f32_16x16x32_bf16(b0, p10, (f32x4){0.f, 0.f, 0.f, 0.f}, 0, 0, 0);
            c0[nt] = __builtin_amdgcn_mfma_f32_16x16x32_bf16(b1, p01, t0, 0, 0, 0);
            c1[nt] = __builtin_amdgcn_mfma_f32_16x16x32_bf16(b1, p11, t1, 0, 0, 0);
        }
    }
#pragma unroll
    for (int nt = 0; nt < 4; ++nt) {
        u16x4 o0, o1;
#pragma unroll
        for (int jj = 0; jj < 4; ++jj) { o0[jj] = f2b(silu(c0[nt][jj])); o1[jj] = f2b(silu(c1[nt][jj])); }
        *(u16x4*)&buf0[e16 * PSTRIDE + nt * 16 + lg * 4] = o0;
        *(u16x4*)&buf1[e16 * PSTRIDE + nt * 16 + lg * 4] = o1;
    }

    // ---- layer 3 (swapped) ----
    {
        const bf16x8 p00 = *(const bf16x8*)&buf0[e16 * PSTRIDE + lg * 8];
        const bf16x8 p01 = *(const bf16x8*)&buf0[e16 * PSTRIDE + 32 + lg * 8];
        const bf16x8 p10 = *(const bf16x8*)&buf1[e16 * PSTRIDE + lg * 8];
        const bf16x8 p11 = *(const bf16x8*)&buf1[e16 * PSTRIDE + 32 + lg * 8];
#pragma unroll
        for (int nt = 0; nt < 4; ++nt) {
            const bf16x8 b0 = *(const bf16x8*)&w2f[nt * 512 + lane * 8];
            const bf16x8 b1 = *(const bf16x8*)&w2f[(4 + nt) * 512 + lane * 8];
            f32x4 t0 = __builtin_amdgcn_mfma_f32_16x16x32_bf16(b0, p00, (f32x4){0.f, 0.f, 0.f, 0.f}, 0, 0, 0);
            f32x4 t1 = __builtin_amdgcn_mfma_f32_16x16x32_bf16(b0, p10, (f32x4){0.f, 0.f, 0.f, 0.f}, 0, 0, 0);
            c0[nt] = __builtin_amdgcn_mfma_f32_16x16x32_bf16(b1, p01, t0, 0, 0, 0);
            c1[nt] = __builtin_amdgcn_mfma_f32_16x16x32_bf16(b1, p11, t1, 0, 0, 0);
        }
    }
#pragma unroll
    for (int nt = 0; nt < 4; ++nt) {
        u16x4 o0, o1;
#pragma unroll
        for (int jj = 0; jj < 4; ++jj) { o0[jj] = f2b(silu(c0[nt][jj])); o1[jj] = f2b(silu(c1[nt][jj])); }
        *(u16x4*)&buf0[e16 * PSTRIDE + nt * 16 + lg * 4] = o0;
        *(u16x4*)&buf1[e16 * PSTRIDE + nt * 16 + lg * 4] = o1;
    }

    // ---- layer 4 (swapped): per-tile sequential store loops ----
    const bf16x8 h00 = *(const bf16x8*)&buf0[e16 * PSTRIDE + lg * 8];
    const bf16x8 h01 = *(const bf16x8*)&buf0[e16 * PSTRIDE + 32 + lg * 8];
    const bf16x8 h10 = *(const bf16x8*)&buf1[e16 * PSTRIDE + lg * 8];
    const bf16x8 h11 = *(const bf16x8*)&buf1[e16 * PSTRIDE + 32 + lg * 8];
#pragma unroll 4
    for (int nt = 0; nt < 16; ++nt) {
        const bf16x8 b0 = *(const bf16x8*)&w3f[nt * 512 + lane * 8];
        const bf16x8 b1 = *(const bf16x8*)&w3f[(16 + nt) * 512 + lane * 8];
        f32x4 cc = __builtin_amdgcn_mfma_f32_16x16x32_bf16(b0, h00, (f32x4){0.f, 0.f, 0.f, 0.f}, 0, 0, 0);
        cc = __builtin_amdgcn_mfma_f32_16x16x32_bf16(b1, h01, cc, 0, 0, 0);
        u16x4 o;
#pragma unroll
        for (int jj = 0; jj < 4; ++jj) o[jj] = f2b(cc[jj]);
        *(u16x4*)&rwb[(g0 + e16) * 256 + nt * 16 + lg * 4] = o;
    }
#pragma unroll 4
    for (int nt = 0; nt < 16; ++nt) {
        const bf16x8 b0 = *(const bf16x8*)&w3f[nt * 512 + lane * 8];
        const bf16x8 b1 = *(const bf16x8*)&w3f[(16 + nt) * 512 + lane * 8];
        f32x4 cc = __builtin_amdgcn_mfma_f32_16x16x32_bf16(b0, h10, (f32x4){0.f, 0.f, 0.f, 0.f}, 0, 0, 0);
        cc = __builtin_amdgcn_mfma_f32_16x16x32_bf16(b1, h11, cc, 0, 0, 0);
        u16x4 o;
#pragma unroll
        for (int jj = 0; jj < 4; ++jj) o[jj] = f2b(cc[jj]);
        *(u16x4*)&rwb[(g1 + e16) * 256 + nt * 16 + lg * 4] = o;
    }
}

// per-edge FMA into acc[16]
#define EDGE_FMA(rv_, f_, y0_, y1_) do { \
    const float p0 = (f_) * b2f((rv_)[0]), p1 = (f_) * b2f((rv_)[1]); \
    const float p2 = (f_) * b2f((rv_)[2]), p3 = (f_) * b2f((rv_)[3]); \
    acc[0]  += p0 * b2f((y0_)[0]); \
    acc[1]  += p1 * b2f((y0_)[1]);  acc[2]  += p1 * b2f((y0_)[2]);  acc[3]  += p1 * b2f((y0_)[3]); \
    acc[4]  += p2 * b2f((y0_)[4]);  acc[5]  += p2 * b2f((y0_)[5]);  acc[6]  += p2 * b2f((y0_)[6]); \
    acc[7]  += p2 * b2f((y0_)[7]);  acc[8]  += p2 * b2f((y1_)[0]); \
    acc[9]  += p3 * b2f((y1_)[1]);  acc[10] += p3 * b2f((y1_)[2]);  acc[11] += p3 * b2f((y1_)[3]); \
    acc[12] += p3 * b2f((y1_)[4]);  acc[13] += p3 * b2f((y1_)[5]);  acc[14] += p3 * b2f((y1_)[6]); \
    acc[15] += p3 * b2f((y1_)[7]); \
} while (0)

// load a 4-edge batch into named buffers (all indices compile-time)
#define LOADBATCH(rv_, f_, y0_, y1_, gb_) do { \
    _Pragma("unroll") \
    for (int j = 0; j < 4; ++j) { \
        const int gg = (gb_) + j; \
        rv_[j] = *(const u16x4*)&rwb[(size_t)gg * 256 + lane * 4]; \
        f_[j]  = feats_in[(size_t)snd_p[gg] * 64 + lane]; \
        y0_[j] = *(const u16x8*)&ybg[(size_t)gg * 16]; \
        y1_[j] = *(const u16x8*)&ybg[(size_t)gg * 16 + 8]; \
    } } while (0)

#define FMABATCH(rv_, f_, y0_, y1_) do { \
    _Pragma("unroll") \
    for (int j = 0; j < 4; ++j) EDGE_FMA(rv_[j], f_[j], y0_[j], y1_[j]); } while (0)

// ---------------------------------------------------------------------------
// msg_accum: one wave per node; DOUBLE-BUFFERED 4-edge batches (A/B named
// register sets). Round-13, unchanged.
// ---------------------------------------------------------------------------
__global__ __launch_bounds__(256) void msg_accum(
    const unsigned short* __restrict__ rwb, const unsigned short* __restrict__ ybg,
    const int* __restrict__ row, const int* __restrict__ snd_p,
    const float* __restrict__ feats_in, unsigned short* __restrict__ Abp)
{
    const int w = threadIdx.x >> 6, lane = threadIdx.x & 63;
    const int n = blockIdx.x * 4 + w;
    const int beg = row[n], end = row[n + 1];

    float acc[16];
#pragma unroll
    for (int m = 0; m < 16; ++m) acc[m] = 0.f;

    u16x4 rvA[4], rvB[4];
    float fA[4], fB[4];
    u16x8 y0A[4], y0B[4], y1A[4], y1B[4];

    const int nb = (end - beg) >> 2;   // full 4-edge batches
    if (nb > 0) {
        LOADBATCH(rvA, fA, y0A, y1A, beg);
        int b = 0;
        while (true) {
            if (b + 1 < nb) LOADBATCH(rvB, fB, y0B, y1B, beg + (b + 1) * 4);
            FMABATCH(rvA, fA, y0A, y1A);
            ++b;
            if (b >= nb) break;
            if (b + 1 < nb) LOADBATCH(rvA, fA, y0A, y1A, beg + (b + 1) * 4);
            FMABATCH(rvB, fB, y0B, y1B);
            ++b;
            if (b >= nb) break;
        }
    }
    for (int g = beg + nb * 4; g < end; ++g) {
        const u16x4 rv = *(const u16x4*)&rwb[(size_t)g * 256 + lane * 4];
        const float f = feats_in[(size_t)snd_p[g] * 64 + lane];
        const u16x8 y0 = *(const u16x8*)&ybg[(size_t)g * 16];
        const u16x8 y1 = *(const u16x8*)&ybg[(size_t)g * 16 + 8];
        EDGE_FMA(rv, f, y0, y1);
    }

#pragma unroll
    for (int m = 0; m < 16; ++m)
        Abp[(size_t)m * 640000 + (size_t)n * 64 + lane] = f2b(acc[m] * INV_AVG);
}

// ---------------------------------------------------------------------------
// einsum_gate (FUSED): block = 16 nodes, 4 waves. Round-12, unchanged.
// ---------------------------------------------------------------------------
__global__ __launch_bounds__(256) void einsum_gate(
    const unsigned short* __restrict__ Abp,   // [16][NN*64] bf16 planes
    const unsigned short* __restrict__ wmixf, // [4 l][8 frag][512] bf16 (per t)
    const float* __restrict__ attrs,
    const float* __restrict__ Wz, const float* __restrict__ Wout,
    const float* __restrict__ wread1, const float* __restrict__ Wr1,
    const float* __restrict__ wr2,
    float* __restrict__ feats_out, float* __restrict__ node_en, int t)
{
    __shared__ unsigned short sNew[16 * NSTR];
    __shared__ float sF[4][64];
    const int w = threadIdx.x >> 6, lane = threadIdx.x & 63;
    const int lg = lane >> 4, n16 = lane & 15;
    const size_t node0 = (size_t)blockIdx.x * 16;

    // ---- phase 1: einsum ----
#pragma unroll
    for (int q = 0; q < 4; ++q) {
        const int m = w * 4 + q;
        const int l = (m == 0) ? 0 : (m < 4) ? 1 : (m < 9) ? 2 : 3;
        const unsigned short* Am = Abp + (size_t)m * 640000;
        const bf16x8 a0 = *(const bf16x8*)&Am[(node0 + n16) * 64 + lg * 8];
        const bf16x8 a1 = *(const bf16x8*)&Am[(node0 + n16) * 64 + 32 + lg * 8];
        const unsigned short* Wl = wmixf + l * 4096;
#pragma unroll
        for (int ct = 0; ct < 4; ++ct) {
            const bf16x8 b0 = *(const bf16x8*)&Wl[ct * 512 + lane * 8];
            const bf16x8 b1 = *(const bf16x8*)&Wl[(4 + ct) * 512 + lane * 8];
            f32x4 cc = __builtin_amdgcn_mfma_f32_16x16x32_bf16(b0, a0, (f32x4){0.f, 0.f, 0.f, 0.f}, 0, 0, 0);
            cc = __builtin_amdgcn_mfma_f32_16x16x32_bf16(b1, a1, cc, 0, 0, 0);
            u16x4 o;
#pragma unroll
            for (int jj = 0; jj < 4; ++jj) o[jj] = f2b(cc[jj]);
            *(u16x4*)&sNew[n16 * NSTR + m * 64 + ct * 16 + lg * 4] = o;
        }
    }
    __syncthreads();

    // ---- phase 2: gate + W_out + energy, wave w owns nodes 4w..4w+3 ----
    for (int qq = 0; qq < 4; ++qq) {
        const int nl = w * 4 + qq;
        const int n = (int)node0 + nl;

        float vals[16];
#pragma unroll
        for (int m = 0; m < 16; ++m)
            vals[m] = b2f(sNew[nl * NSTR + m * 64 + lane]);

        const float s1 = vals[0];
        float inv2 = 0.f;
#pragma unroll
        for (int m = 0; m < 16; ++m) inv2 += vals[m] * vals[m];

        float z0 = 0.f, z1 = 0.f, z2 = 0.f;
#pragma unroll
        for (int zz = 0; zz < NZ; ++zz) {
            const float a = attrs[n * NZ + zz];
            z0 += a * Wz[(t * 3 + 0) * 640 + zz * 64 + lane];
            z1 += a * Wz[(t * 3 + 1) * 640 + zz * 64 + lane];
            z2 += a * Wz[(t * 3 + 2) * 640 + zz * 64 + lane];
        }
        const float b = z0 * s1 + z1 * inv2 + z2 * (s1 * inv2);

        sF[w][lane] = b;
        float fnew = 0.f;
#pragma unroll 8
        for (int j = 0; j < 64; ++j) fnew += sF[w][j] * Wout[j * 64 + lane];
        feats_out[(size_t)n * 64 + lane] = fnew;

        if (t == 0) {
            float v = fnew * wread1[lane];
#pragma unroll
            for (int off = 32; off > 0; off >>= 1) v += __shfl_down(v, off, 64);
            if (lane == 0) node_en[n] += v;
        } else {
            sF[w][lane] = fnew;
            if (lane < 16) {
                float a = 0.f;
#pragma unroll 8
                for (int j = 0; j < 64; ++j) a += sF[w][j] * Wr1[j * 16 + lane];
                float vv = silu(a) * wr2[lane];
                vv += __shfl_down(vv, 8, 64);
                vv += __shfl_down(vv, 4, 64);
                vv += __shfl_down(vv, 2, 64);
                vv += __shfl_down(vv, 1, 64);
                if (lane == 0) node_en[n] += vv;
            }
        }
    }
}

// ---------------------------------------------------------------------------
// final_reduce: single block; LDS per-graph accumulation, plain stores.
// ---------------------------------------------------------------------------
__global__ __launch_bounds__(1024) void final_reduce(
    const float* __restrict__ node_en, const int* __restrict__ batch,
    float* __restrict__ out)
{
    __shared__ float sg[NG];
    if (threadIdx.x < NG) sg[threadIdx.x] = 0.f;
    __syncthreads();
    for (int n = threadIdx.x; n < NN; n += 1024)
        atomicAdd(&sg[batch[n]], node_en[n]);
    __syncthreads();
    if (threadIdx.x < NG) out[threadIdx.x] = sg[threadIdx.x];
}

// ---------------------------------------------------------------------------
extern "C" void kernel_launch(void* const* d_in, const int* in_sizes, int n_in,
                              void* d_out, int out_size, void* d_ws, size_t ws_size,
                              hipStream_t stream) {
    const float* attrs   = (const float*)d_in[0];
    const float* pos     = (const float*)d_in[1];
    const int*   ei      = (const int*)d_in[2];
    const int*   batch   = (const int*)d_in[3];
    const float* ae      = (const float*)d_in[4];
    const float* W_embed = (const float*)d_in[5];
    const float* rW0     = (const float*)d_in[6];
    const float* rW1     = (const float*)d_in[7];
    const float* rW2     = (const float*)d_in[8];
    const float* rW3     = (const float*)d_in[9];
    const float* Wmix    = (const float*)d_in[10];
    const float* Wz      = (const float*)d_in[11];
    const float* Wout    = (const float*)d_in[12];
    const float* wread1  = (const float*)d_in[13];
    const float* Wr1     = (const float*)d_in[14];
    const float* wr2     = (const float*)d_in[15];
    float* out = (float*)d_out;

    char* ws = (char*)d_ws;
    unsigned short* rwb  = (unsigned short*)(ws);                 // [NE][256] bf16 = 81,920,000
    unsigned short* ybg  = (unsigned short*)(ws + 81920000);      // [NE][16] bf16  =  5,120,000
    unsigned short* ebg  = (unsigned short*)(ws + 87040000);      // [NE][8] bf16   =  2,560,000
    float* feats0        = (float*)(ws + 89600000);               //  2,560,000
    float* feats1        = (float*)(ws + 92160000);               //  2,560,000
    unsigned short* Abp  = (unsigned short*)(ws + 94720000);      // [16][NN*64] bf16 = 20,480,000
    unsigned short* w0f  = (unsigned short*)(ws + 115200000);     //      8,192
    unsigned short* w1f  = (unsigned short*)(ws + 115208192);     //     32,768
    unsigned short* w2f  = (unsigned short*)(ws + 115240960);     //     32,768
    unsigned short* w3f  = (unsigned short*)(ws + 115273728);     //     65,536
    unsigned short* wmixf= (unsigned short*)(ws + 115339264);     //     65,536
    int* cnt             = (int*)(ws + 115404800);                //     40,960
    int* cur             = (int*)(ws + 115445760);                //     40,960
    int* rowst           = (int*)(ws + 115486720);                //     40,976 (padded)
    int* perm            = (int*)(ws + 115527696);                //    640,000
    int* snd_p           = (int*)(ws + 116167696);                //    640,000
    float* node_en       = (float*)(ws + 116807696);              //     40,000

    hipMemsetAsync(cnt, 0, 81920, stream);   // cnt + cur contiguous

    node_init<<<2500, 256, 0, stream>>>(attrs, W_embed, ae, feats0, node_en);

    csr_count<<<625, 256, 0, stream>>>(ei, cnt);
    csr_scan<<<1, 1024, 0, stream>>>(cnt, rowst);
    csr_scatter<<<625, 256, 0, stream>>>(ei, rowst, cur, perm);

    w_prep<<<400, 256, 0, stream>>>(rW0, rW1, rW2, rW3, Wmix,
                                    w0f, w1f, w2f, w3f, wmixf);
    edge_geom<<<625, 256, 0, stream>>>(ei, pos, perm, ybg, ebg, snd_p);

    for (int t = 0; t < 2; ++t) {
        radial_fused<<<1250, 256, 0, stream>>>(
            ebg, w0f + t * 2048, w1f + t * 8192, w2f + t * 8192, w3f + t * 16384, rwb);
        msg_accum<<<2500, 256, 0, stream>>>(
            rwb, ybg, rowst, snd_p, (t == 0) ? feats0 : feats1, Abp);
        einsum_gate<<<625, 256, 0, stream>>>(
            Abp, wmixf + t * 16384, attrs, Wz, Wout + t * 4096,
            wread1, Wr1, wr2,
            (t == 0) ? feats1 : feats0, node_en, t);
    }
    final_reduce<<<1, 1024, 0, stream>>>(node_en, batch, out);
}

// Round 16
// 260.366 us; speedup vs baseline: 1.0102x; 1.0102x over previous
//
#include <hip/hip_runtime.h>
#include <hip/hip_bf16.h>
#include <math.h>

#define NN 10000
#define NE 160000
#define NG 20
#define NZ 10
#define INV_AVG 0.0625f
#define PSTRIDE 76    // LDS row stride (elems): 8B-aligned, conflict-free
#define NSTR 1040     // einsum_gate sNew node stride (elems)

typedef __attribute__((ext_vector_type(8))) short bf16x8;
typedef __attribute__((ext_vector_type(4))) float f32x4;
typedef __attribute__((ext_vector_type(4))) unsigned short u16x4;
typedef __attribute__((ext_vector_type(8))) unsigned short u16x8;

// fast silu: rcp is ~1ulp@2^-22 — outputs are bf16-rounded anyway
__device__ __forceinline__ float silu(float x) {
    return x * __builtin_amdgcn_rcpf(1.0f + __expf(-x));
}

__device__ __forceinline__ unsigned short f2b(float f) {
    union { float f; unsigned u; } v; v.f = f;
    unsigned r = v.u + 0x7FFF + ((v.u >> 16) & 1);
    return (unsigned short)(r >> 16);
}
__device__ __forceinline__ float b2f(unsigned short h) {
    union { unsigned u; float f; } v; v.u = ((unsigned)h) << 16; return v.f;
}

// ---------------------------------------------------------------------------
// feats0 = node_attrs @ W_embed ; node_en[n] = node_attrs @ atomic_energies
// ---------------------------------------------------------------------------
__global__ __launch_bounds__(256) void node_init(
    const float* __restrict__ attrs, const float* __restrict__ W_embed,
    const float* __restrict__ ae,
    float* __restrict__ feats, float* __restrict__ node_en)
{
    int gid = blockIdx.x * blockDim.x + threadIdx.x;
    if (gid >= NN * 64) return;
    int n = gid >> 6, k = gid & 63;
    float acc = 0.f;
#pragma unroll
    for (int z = 0; z < NZ; ++z) acc += attrs[n * NZ + z] * W_embed[z * 64 + k];
    feats[gid] = acc;
    if (k == 0) {
        float e0 = 0.f;
#pragma unroll
        for (int z = 0; z < NZ; ++z) e0 += attrs[n * NZ + z] * ae[z];
        node_en[n] = e0;
    }
}

// ---------------------------------------------------------------------------
// CSR build
// ---------------------------------------------------------------------------
__global__ __launch_bounds__(256) void csr_count(const int* __restrict__ ei, int* __restrict__ cnt)
{
    int e = blockIdx.x * 256 + threadIdx.x;
    if (e < NE) atomicAdd(&cnt[ei[NE + e]], 1);
}

__global__ __launch_bounds__(1024) void csr_scan(const int* __restrict__ cnt, int* __restrict__ row)
{
    __shared__ int part[1024];
    const int tid = threadIdx.x;
    const int base = tid * 10;
    int loc[10];
    int s = 0;
#pragma unroll
    for (int q = 0; q < 10; ++q) {
        int idx = base + q;
        int v = (idx < NN) ? cnt[idx] : 0;
        loc[q] = s; s += v;
    }
    part[tid] = s;
    __syncthreads();
    for (int off = 1; off < 1024; off <<= 1) {
        int v = (tid >= off) ? part[tid - off] : 0;
        __syncthreads();
        part[tid] += v;
        __syncthreads();
    }
    int pre = (tid > 0) ? part[tid - 1] : 0;
#pragma unroll
    for (int q = 0; q < 10; ++q) {
        int idx = base + q;
        if (idx < NN) row[idx] = pre + loc[q];
    }
    if (tid == 1023) row[NN] = part[1023];
}

__global__ __launch_bounds__(256) void csr_scatter(
    const int* __restrict__ ei, const int* __restrict__ row,
    int* __restrict__ cur, int* __restrict__ perm)
{
    int e = blockIdx.x * 256 + threadIdx.x;
    if (e < NE) {
        int r = ei[NE + e];
        int p = atomicAdd(&cur[r], 1);
        perm[row[r] + p] = e;
    }
}

// ---------------------------------------------------------------------------
// w_prep: pack radial + Wmix weights into bf16 MFMA fragment order:
// fragment (kt,nt), lane l, elem j holds W[kt*32 + (l>>4)*8 + j][nt*16 + (l&15)].
// ---------------------------------------------------------------------------
__global__ __launch_bounds__(256) void w_prep(
    const float* __restrict__ rW0, const float* __restrict__ rW1,
    const float* __restrict__ rW2, const float* __restrict__ rW3,
    const float* __restrict__ Wmix,
    unsigned short* __restrict__ w0f, unsigned short* __restrict__ w1f,
    unsigned short* __restrict__ w2f, unsigned short* __restrict__ w3f,
    unsigned short* __restrict__ wmixf)
{
    int g = blockIdx.x * 256 + threadIdx.x;   // 102400 total
    if (g < 4096) {
        int t = g >> 11, x = g & 2047;
        int nt = x >> 9, l = (x >> 3) & 63, j = x & 7;
        int k = (l >> 4) * 8 + j, c = nt * 16 + (l & 15);
        w0f[g] = (k < 8) ? f2b(rW0[t * 512 + k * 64 + c]) : (unsigned short)0;
    } else if (g < 20480) {
        int x0 = g - 4096;
        int t = x0 >> 13, x = x0 & 8191;
        int fidx = x >> 9, l = (x >> 3) & 63, j = x & 7;
        int kt = fidx >> 2, nt = fidx & 3;
        int k = kt * 32 + (l >> 4) * 8 + j, c = nt * 16 + (l & 15);
        w1f[x0] = f2b(rW1[t * 4096 + k * 64 + c]);
    } else if (g < 36864) {
        int x0 = g - 20480;
        int t = x0 >> 13, x = x0 & 8191;
        int fidx = x >> 9, l = (x >> 3) & 63, j = x & 7;
        int kt = fidx >> 2, nt = fidx & 3;
        int k = kt * 32 + (l >> 4) * 8 + j, c = nt * 16 + (l & 15);
        w2f[x0] = f2b(rW2[t * 4096 + k * 64 + c]);
    } else if (g < 69632) {
        int x0 = g - 36864;
        int t = x0 >> 14, x = x0 & 16383;
        int fidx = x >> 9, l = (x >> 3) & 63, j = x & 7;
        int kt = fidx >> 4, nt = fidx & 15;
        int k = kt * 32 + (l >> 4) * 8 + j, c = nt * 16 + (l & 15);
        w3f[x0] = f2b(rW3[t * 16384 + k * 256 + c]);
    } else if (g < 102400) {
        int x0 = g - 69632;
        int t = x0 >> 14;
        int x = x0 & 16383;
        int l = x >> 12;
        int xx = x & 4095;
        int f = xx >> 9, ll = (xx >> 3) & 63, j = xx & 7;
        int kt = f >> 2, ct = f & 3;
        int k = kt * 32 + (ll >> 4) * 8 + j, c = ct * 16 + (ll & 15);
        wmixf[x0] = f2b(Wmix[t * 16384 + l * 4096 + k * 64 + c]);
    }
}

// ---------------------------------------------------------------------------
// edge_geom (runs ONCE): per PERMUTED edge slot g, compute Y (bf16), radial
// basis eb (bf16), and sender index. All outputs receiver-sorted.
// ---------------------------------------------------------------------------
__global__ __launch_bounds__(256) void edge_geom(
    const int* __restrict__ ei, const float* __restrict__ pos,
    const int* __restrict__ perm,
    unsigned short* __restrict__ ybg, unsigned short* __restrict__ ebg,
    int* __restrict__ snd_p)
{
    const int g = blockIdx.x * 256 + threadIdx.x;   // grid covers exactly NE
    const int e = perm[g];
    const int snd = ei[e], rcv = ei[NE + e];
    snd_p[g] = snd;
    const float dx = pos[rcv * 3 + 0] - pos[snd * 3 + 0];
    const float dy = pos[rcv * 3 + 1] - pos[snd * 3 + 1];
    const float dz = pos[rcv * 3 + 2] - pos[snd * 3 + 2];
    const float r = sqrtf(dx * dx + dy * dy + dz * dz + 1e-12f);
    const float ir = 1.0f / r;
    const float x = dx * ir, y = dy * ir, z = dz * ir;
    const float xx = x * x, yy = y * y, zz = z * z;

    u16x8 ylo, yhi;
    ylo[0] = f2b(1.0f);
    ylo[1] = f2b(1.73205081f * x);
    ylo[2] = f2b(1.73205081f * y);
    ylo[3] = f2b(1.73205081f * z);
    ylo[4] = f2b(3.87298335f * x * y);
    ylo[5] = f2b(3.87298335f * y * z);
    ylo[6] = f2b(1.11803399f * (3.0f * zz - 1.0f));
    ylo[7] = f2b(3.87298335f * x * z);
    yhi[0] = f2b(1.93649167f * (xx - yy));
    yhi[1] = f2b(2.09165007f * y * (3.0f * xx - yy));
    yhi[2] = f2b(10.2469508f * x * y * z);
    yhi[3] = f2b(1.62018517f * y * (5.0f * zz - 1.0f));
    yhi[4] = f2b(1.32287566f * z * (5.0f * zz - 3.0f));
    yhi[5] = f2b(1.62018517f * x * (5.0f * zz - 1.0f));
    yhi[6] = f2b(5.12347538f * z * (xx - yy));
    yhi[7] = f2b(2.09165007f * x * (xx - 3.0f * yy));
    *(u16x8*)&ybg[(size_t)g * 16] = ylo;
    *(u16x8*)&ybg[(size_t)g * 16 + 8] = yhi;

    const float u = r * 0.2f;
    float env = 0.0f;
    if (u < 1.0f) {
        const float u2 = u * u, u5 = u2 * u2 * u;
        env = 1.0f - 21.0f * u5 + 35.0f * u5 * u - 15.0f * u5 * u2;
    }
    const float cb = 0.632455532f * ir * env;
    const float pu = 3.14159265358979f * u;
    u16x8 eb;
#pragma unroll
    for (int i = 0; i < 8; ++i) eb[i] = f2b(cb * __sinf((float)(i + 1) * pu));
    *(u16x8*)&ebg[(size_t)g * 8] = eb;
}

// ---------------------------------------------------------------------------
// radial_fused: ONE 16-edge tile per wave, all-swapped-operand MFMAs,
// vectorized u16x4 bounces, SINGLE LDS buffer (reads are issued before the
// same layer's writes; DS ops execute in program order per wave — validated
// round 15, absmax 0). LDS = 9728 B/block -> 16-block/CU LDS cap, whole
// 2500-block grid co-resident in one batch for max latency hiding.
// ---------------------------------------------------------------------------
__global__ __launch_bounds__(256) void radial_fused(
    const unsigned short* __restrict__ ebg,
    const unsigned short* __restrict__ w0f,
    const unsigned short* __restrict__ w1f,
    const unsigned short* __restrict__ w2f,
    const unsigned short* __restrict__ w3f,
    unsigned short* __restrict__ rwb)
{
    __shared__ unsigned short sP[4][16 * PSTRIDE];
    const int w = threadIdx.x >> 6, lane = threadIdx.x & 63;
    const int tIdx = blockIdx.x * 4 + w;
    const int lg = lane >> 4, e16 = lane & 15;
    unsigned short* buf = &sP[w][0];

    const size_t g0 = (size_t)tIdx * 16;
    f32x4 c[4];

    // ---- layer 1 (swapped): C[ch][edge] = W0^T · eb^T ----
    bf16x8 a1 = {0, 0, 0, 0, 0, 0, 0, 0};
    if (lg == 0) a1 = *(const bf16x8*)&ebg[(g0 + e16) * 8];
#pragma unroll
    for (int nt = 0; nt < 4; ++nt) {
        const bf16x8 b = *(const bf16x8*)&w0f[nt * 512 + lane * 8];
        c[nt] = __builtin_amdgcn_mfma_f32_16x16x32_bf16(b, a1, (f32x4){0.f, 0.f, 0.f, 0.f}, 0, 0, 0);
    }
#pragma unroll
    for (int nt = 0; nt < 4; ++nt) {
        u16x4 o;
#pragma unroll
        for (int jj = 0; jj < 4; ++jj) o[jj] = f2b(silu(c[nt][jj]));
        *(u16x4*)&buf[e16 * PSTRIDE + nt * 16 + lg * 4] = o;
    }

    // ---- layer 2 (swapped, single buffer: reads issued before writes) ----
    {
        const bf16x8 ak0 = *(const bf16x8*)&buf[e16 * PSTRIDE + lg * 8];
        const bf16x8 ak1 = *(const bf16x8*)&buf[e16 * PSTRIDE + 32 + lg * 8];
#pragma unroll
        for (int nt = 0; nt < 4; ++nt) {
            const bf16x8 b0 = *(const bf16x8*)&w1f[nt * 512 + lane * 8];
            const bf16x8 b1 = *(const bf16x8*)&w1f[(4 + nt) * 512 + lane * 8];
            f32x4 acc = __builtin_amdgcn_mfma_f32_16x16x32_bf16(b0, ak0, (f32x4){0.f, 0.f, 0.f, 0.f}, 0, 0, 0);
            c[nt] = __builtin_amdgcn_mfma_f32_16x16x32_bf16(b1, ak1, acc, 0, 0, 0);
        }
    }
#pragma unroll
    for (int nt = 0; nt < 4; ++nt) {
        u16x4 o;
#pragma unroll
        for (int jj = 0; jj < 4; ++jj) o[jj] = f2b(silu(c[nt][jj]));
        *(u16x4*)&buf[e16 * PSTRIDE + nt * 16 + lg * 4] = o;
    }

    // ---- layer 3 (swapped) ----
    {
        const bf16x8 ak0 = *(const bf16x8*)&buf[e16 * PSTRIDE + lg * 8];
        const bf16x8 ak1 = *(const bf16x8*)&buf[e16 * PSTRIDE + 32 + lg * 8];
#pragma unroll
        for (int nt = 0; nt < 4; ++nt) {
            const bf16x8 b0 = *(const bf16x8*)&w2f[nt * 512 + lane * 8];
            const bf16x8 b1 = *(const bf16x8*)&w2f[(4 + nt) * 512 + lane * 8];
            f32x4 acc = __builtin_amdgcn_mfma_f32_16x16x32_bf16(b0, ak0, (f32x4){0.f, 0.f, 0.f, 0.f}, 0, 0, 0);
            c[nt] = __builtin_amdgcn_mfma_f32_16x16x32_bf16(b1, ak1, acc, 0, 0, 0);
        }
    }
#pragma unroll
    for (int nt = 0; nt < 4; ++nt) {
        u16x4 o;
#pragma unroll
        for (int jj = 0; jj < 4; ++jj) o[jj] = f2b(silu(c[nt][jj]));
        *(u16x4*)&buf[e16 * PSTRIDE + nt * 16 + lg * 4] = o;
    }

    // ---- layer 4 (swapped): lane holds c = nt*16 + lg*4 + jj ----
    {
        const bf16x8 h0 = *(const bf16x8*)&buf[e16 * PSTRIDE + lg * 8];
        const bf16x8 h1 = *(const bf16x8*)&buf[e16 * PSTRIDE + 32 + lg * 8];
#pragma unroll 4
        for (int nt = 0; nt < 16; ++nt) {
            const bf16x8 b0 = *(const bf16x8*)&w3f[nt * 512 + lane * 8];
            const bf16x8 b1 = *(const bf16x8*)&w3f[(16 + nt) * 512 + lane * 8];
            f32x4 cc = __builtin_amdgcn_mfma_f32_16x16x32_bf16(b0, h0, (f32x4){0.f, 0.f, 0.f, 0.f}, 0, 0, 0);
            cc = __builtin_amdgcn_mfma_f32_16x16x32_bf16(b1, h1, cc, 0, 0, 0);
            u16x4 o;
#pragma unroll
            for (int jj = 0; jj < 4; ++jj) o[jj] = f2b(cc[jj]);
            *(u16x4*)&rwb[(g0 + e16) * 256 + nt * 16 + lg * 4] = o;
        }
    }
}

// per-edge FMA into acc[16]
#define EDGE_FMA(rv_, f_, y0_, y1_) do { \
    const float p0 = (f_) * b2f((rv_)[0]), p1 = (f_) * b2f((rv_)[1]); \
    const float p2 = (f_) * b2f((rv_)[2]), p3 = (f_) * b2f((rv_)[3]); \
    acc[0]  += p0 * b2f((y0_)[0]); \
    acc[1]  += p1 * b2f((y0_)[1]);  acc[2]  += p1 * b2f((y0_)[2]);  acc[3]  += p1 * b2f((y0_)[3]); \
    acc[4]  += p2 * b2f((y0_)[4]);  acc[5]  += p2 * b2f((y0_)[5]);  acc[6]  += p2 * b2f((y0_)[6]); \
    acc[7]  += p2 * b2f((y0_)[7]);  acc[8]  += p2 * b2f((y1_)[0]); \
    acc[9]  += p3 * b2f((y1_)[1]);  acc[10] += p3 * b2f((y1_)[2]);  acc[11] += p3 * b2f((y1_)[3]); \
    acc[12] += p3 * b2f((y1_)[4]);  acc[13] += p3 * b2f((y1_)[5]);  acc[14] += p3 * b2f((y1_)[6]); \
    acc[15] += p3 * b2f((y1_)[7]); \
} while (0)

// load a 4-edge batch into named buffers (all indices compile-time)
#define LOADBATCH(rv_, f_, y0_, y1_, gb_) do { \
    _Pragma("unroll") \
    for (int j = 0; j < 4; ++j) { \
        const int gg = (gb_) + j; \
        rv_[j] = *(const u16x4*)&rwb[(size_t)gg * 256 + lane * 4]; \
        f_[j]  = feats_in[(size_t)snd_p[gg] * 64 + lane]; \
        y0_[j] = *(const u16x8*)&ybg[(size_t)gg * 16]; \
        y1_[j] = *(const u16x8*)&ybg[(size_t)gg * 16 + 8]; \
    } } while (0)

#define FMABATCH(rv_, f_, y0_, y1_) do { \
    _Pragma("unroll") \
    for (int j = 0; j < 4; ++j) EDGE_FMA(rv_[j], f_[j], y0_[j], y1_[j]); } while (0)

// ---------------------------------------------------------------------------
// msg_accum: one wave per node; DOUBLE-BUFFERED 4-edge batches (A/B named
// register sets). Round-13, unchanged.
// ---------------------------------------------------------------------------
__global__ __launch_bounds__(256) void msg_accum(
    const unsigned short* __restrict__ rwb, const unsigned short* __restrict__ ybg,
    const int* __restrict__ row, const int* __restrict__ snd_p,
    const float* __restrict__ feats_in, unsigned short* __restrict__ Abp)
{
    const int w = threadIdx.x >> 6, lane = threadIdx.x & 63;
    const int n = blockIdx.x * 4 + w;
    const int beg = row[n], end = row[n + 1];

    float acc[16];
#pragma unroll
    for (int m = 0; m < 16; ++m) acc[m] = 0.f;

    u16x4 rvA[4], rvB[4];
    float fA[4], fB[4];
    u16x8 y0A[4], y0B[4], y1A[4], y1B[4];

    const int nb = (end - beg) >> 2;   // full 4-edge batches
    if (nb > 0) {
        LOADBATCH(rvA, fA, y0A, y1A, beg);
        int b = 0;
        while (true) {
            if (b + 1 < nb) LOADBATCH(rvB, fB, y0B, y1B, beg + (b + 1) * 4);
            FMABATCH(rvA, fA, y0A, y1A);
            ++b;
            if (b >= nb) break;
            if (b + 1 < nb) LOADBATCH(rvA, fA, y0A, y1A, beg + (b + 1) * 4);
            FMABATCH(rvB, fB, y0B, y1B);
            ++b;
            if (b >= nb) break;
        }
    }
    for (int g = beg + nb * 4; g < end; ++g) {
        const u16x4 rv = *(const u16x4*)&rwb[(size_t)g * 256 + lane * 4];
        const float f = feats_in[(size_t)snd_p[g] * 64 + lane];
        const u16x8 y0 = *(const u16x8*)&ybg[(size_t)g * 16];
        const u16x8 y1 = *(const u16x8*)&ybg[(size_t)g * 16 + 8];
        EDGE_FMA(rv, f, y0, y1);
    }

#pragma unroll
    for (int m = 0; m < 16; ++m)
        Abp[(size_t)m * 640000 + (size_t)n * 64 + lane] = f2b(acc[m] * INV_AVG);
}

// ---------------------------------------------------------------------------
// einsum_gate (FUSED): block = 16 nodes, 4 waves. Round-12, unchanged.
// ---------------------------------------------------------------------------
__global__ __launch_bounds__(256) void einsum_gate(
    const unsigned short* __restrict__ Abp,   // [16][NN*64] bf16 planes
    const unsigned short* __restrict__ wmixf, // [4 l][8 frag][512] bf16 (per t)
    const float* __restrict__ attrs,
    const float* __restrict__ Wz, const float* __restrict__ Wout,
    const float* __restrict__ wread1, const float* __restrict__ Wr1,
    const float* __restrict__ wr2,
    float* __restrict__ feats_out, float* __restrict__ node_en, int t)
{
    __shared__ unsigned short sNew[16 * NSTR];
    __shared__ float sF[4][64];
    const int w = threadIdx.x >> 6, lane = threadIdx.x & 63;
    const int lg = lane >> 4, n16 = lane & 15;
    const size_t node0 = (size_t)blockIdx.x * 16;

    // ---- phase 1: einsum ----
#pragma unroll
    for (int q = 0; q < 4; ++q) {
        const int m = w * 4 + q;
        const int l = (m == 0) ? 0 : (m < 4) ? 1 : (m < 9) ? 2 : 3;
        const unsigned short* Am = Abp + (size_t)m * 640000;
        const bf16x8 a0 = *(const bf16x8*)&Am[(node0 + n16) * 64 + lg * 8];
        const bf16x8 a1 = *(const bf16x8*)&Am[(node0 + n16) * 64 + 32 + lg * 8];
        const unsigned short* Wl = wmixf + l * 4096;
#pragma unroll
        for (int ct = 0; ct < 4; ++ct) {
            const bf16x8 b0 = *(const bf16x8*)&Wl[ct * 512 + lane * 8];
            const bf16x8 b1 = *(const bf16x8*)&Wl[(4 + ct) * 512 + lane * 8];
            f32x4 cc = __builtin_amdgcn_mfma_f32_16x16x32_bf16(b0, a0, (f32x4){0.f, 0.f, 0.f, 0.f}, 0, 0, 0);
            cc = __builtin_amdgcn_mfma_f32_16x16x32_bf16(b1, a1, cc, 0, 0, 0);
            u16x4 o;
#pragma unroll
            for (int jj = 0; jj < 4; ++jj) o[jj] = f2b(cc[jj]);
            *(u16x4*)&sNew[n16 * NSTR + m * 64 + ct * 16 + lg * 4] = o;
        }
    }
    __syncthreads();

    // ---- phase 2: gate + W_out + energy, wave w owns nodes 4w..4w+3 ----
    for (int qq = 0; qq < 4; ++qq) {
        const int nl = w * 4 + qq;
        const int n = (int)node0 + nl;

        float vals[16];
#pragma unroll
        for (int m = 0; m < 16; ++m)
            vals[m] = b2f(sNew[nl * NSTR + m * 64 + lane]);

        const float s1 = vals[0];
        float inv2 = 0.f;
#pragma unroll
        for (int m = 0; m < 16; ++m) inv2 += vals[m] * vals[m];

        float z0 = 0.f, z1 = 0.f, z2 = 0.f;
#pragma unroll
        for (int zz = 0; zz < NZ; ++zz) {
            const float a = attrs[n * NZ + zz];
            z0 += a * Wz[(t * 3 + 0) * 640 + zz * 64 + lane];
            z1 += a * Wz[(t * 3 + 1) * 640 + zz * 64 + lane];
            z2 += a * Wz[(t * 3 + 2) * 640 + zz * 64 + lane];
        }
        const float b = z0 * s1 + z1 * inv2 + z2 * (s1 * inv2);

        sF[w][lane] = b;
        float fnew = 0.f;
#pragma unroll 8
        for (int j = 0; j < 64; ++j) fnew += sF[w][j] * Wout[j * 64 + lane];
        feats_out[(size_t)n * 64 + lane] = fnew;

        if (t == 0) {
            float v = fnew * wread1[lane];
#pragma unroll
            for (int off = 32; off > 0; off >>= 1) v += __shfl_down(v, off, 64);
            if (lane == 0) node_en[n] += v;
        } else {
            sF[w][lane] = fnew;
            if (lane < 16) {
                float a = 0.f;
#pragma unroll 8
                for (int j = 0; j < 64; ++j) a += sF[w][j] * Wr1[j * 16 + lane];
                float vv = silu(a) * wr2[lane];
                vv += __shfl_down(vv, 8, 64);
                vv += __shfl_down(vv, 4, 64);
                vv += __shfl_down(vv, 2, 64);
                vv += __shfl_down(vv, 1, 64);
                if (lane == 0) node_en[n] += vv;
            }
        }
    }
}

// ---------------------------------------------------------------------------
// final_reduce: single block; LDS per-graph accumulation, plain stores.
// ---------------------------------------------------------------------------
__global__ __launch_bounds__(1024) void final_reduce(
    const float* __restrict__ node_en, const int* __restrict__ batch,
    float* __restrict__ out)
{
    __shared__ float sg[NG];
    if (threadIdx.x < NG) sg[threadIdx.x] = 0.f;
    __syncthreads();
    for (int n = threadIdx.x; n < NN; n += 1024)
        atomicAdd(&sg[batch[n]], node_en[n]);
    __syncthreads();
    if (threadIdx.x < NG) out[threadIdx.x] = sg[threadIdx.x];
}

// ---------------------------------------------------------------------------
extern "C" void kernel_launch(void* const* d_in, const int* in_sizes, int n_in,
                              void* d_out, int out_size, void* d_ws, size_t ws_size,
                              hipStream_t stream) {
    const float* attrs   = (const float*)d_in[0];
    const float* pos     = (const float*)d_in[1];
    const int*   ei      = (const int*)d_in[2];
    const int*   batch   = (const int*)d_in[3];
    const float* ae      = (const float*)d_in[4];
    const float* W_embed = (const float*)d_in[5];
    const float* rW0     = (const float*)d_in[6];
    const float* rW1     = (const float*)d_in[7];
    const float* rW2     = (const float*)d_in[8];
    const float* rW3     = (const float*)d_in[9];
    const float* Wmix    = (const float*)d_in[10];
    const float* Wz      = (const float*)d_in[11];
    const float* Wout    = (const float*)d_in[12];
    const float* wread1  = (const float*)d_in[13];
    const float* Wr1     = (const float*)d_in[14];
    const float* wr2     = (const float*)d_in[15];
    float* out = (float*)d_out;

    char* ws = (char*)d_ws;
    unsigned short* rwb  = (unsigned short*)(ws);                 // [NE][256] bf16 = 81,920,000
    unsigned short* ybg  = (unsigned short*)(ws + 81920000);      // [NE][16] bf16  =  5,120,000
    unsigned short* ebg  = (unsigned short*)(ws + 87040000);      // [NE][8] bf16   =  2,560,000
    float* feats0        = (float*)(ws + 89600000);               //  2,560,000
    float* feats1        = (float*)(ws + 92160000);               //  2,560,000
    unsigned short* Abp  = (unsigned short*)(ws + 94720000);      // [16][NN*64] bf16 = 20,480,000
    unsigned short* w0f  = (unsigned short*)(ws + 115200000);     //      8,192
    unsigned short* w1f  = (unsigned short*)(ws + 115208192);     //     32,768
    unsigned short* w2f  = (unsigned short*)(ws + 115240960);     //     32,768
    unsigned short* w3f  = (unsigned short*)(ws + 115273728);     //     65,536
    unsigned short* wmixf= (unsigned short*)(ws + 115339264);     //     65,536
    int* cnt             = (int*)(ws + 115404800);                //     40,960
    int* cur             = (int*)(ws + 115445760);                //     40,960
    int* rowst           = (int*)(ws + 115486720);                //     40,976 (padded)
    int* perm            = (int*)(ws + 115527696);                //    640,000
    int* snd_p           = (int*)(ws + 116167696);                //    640,000
    float* node_en       = (float*)(ws + 116807696);              //     40,000

    hipMemsetAsync(cnt, 0, 81920, stream);   // cnt + cur contiguous

    node_init<<<2500, 256, 0, stream>>>(attrs, W_embed, ae, feats0, node_en);

    csr_count<<<625, 256, 0, stream>>>(ei, cnt);
    csr_scan<<<1, 1024, 0, stream>>>(cnt, rowst);
    csr_scatter<<<625, 256, 0, stream>>>(ei, rowst, cur, perm);

    w_prep<<<400, 256, 0, stream>>>(rW0, rW1, rW2, rW3, Wmix,
                                    w0f, w1f, w2f, w3f, wmixf);
    edge_geom<<<625, 256, 0, stream>>>(ei, pos, perm, ybg, ebg, snd_p);

    for (int t = 0; t < 2; ++t) {
        radial_fused<<<2500, 256, 0, stream>>>(
            ebg, w0f + t * 2048, w1f + t * 8192, w2f + t * 8192, w3f + t * 16384, rwb);
        msg_accum<<<2500, 256, 0, stream>>>(
            rwb, ybg, rowst, snd_p, (t == 0) ? feats0 : feats1, Abp);
        einsum_gate<<<625, 256, 0, stream>>>(
            Abp, wmixf + t * 16384, attrs, Wz, Wout + t * 4096,
            wread1, Wr1, wr2,
            (t == 0) ? feats1 : feats0, node_en, t);
    }
    final_reduce<<<1, 1024, 0, stream>>>(node_en, batch, out);
}